// Round 16
// baseline (106.602 us; speedup 1.0000x reference)
//
#include <hip/hip_runtime.h>
#include <math.h>

#define NB      8192
#define HLEN    200
#define DIM     128
#define AH      64
#define NITEMS  100000
#define NTILE   13
#define CONV_BLKS 1024
#define INTER_BLKS 1024        // 8 b per inter block (2 groups of 4)
#define PREP_BLKS (CONV_BLKS + INTER_BLKS)   // 2048, roles interleaved mod 2

typedef __attribute__((ext_vector_type(4))) float f32x4;
typedef __attribute__((ext_vector_type(2))) float f32x2;
typedef __attribute__((ext_vector_type(4))) int   i32x4;
typedef __attribute__((ext_vector_type(8))) short bf16x8;
typedef unsigned int uint;

__device__ __forceinline__ unsigned short f2bf(float f) {
  uint u = __float_as_uint(f);
  u += 0x7fffu + ((u >> 16) & 1u);
  return (unsigned short)(u >> 16);
}
__device__ __forceinline__ float bf2f(unsigned short h) {
  return __uint_as_float(((uint)h) << 16);
}
__device__ __forceinline__ long pick64(const i32x4& v, int h) {
  return (long)(unsigned)v[2 * h] | ((long)(unsigned)v[2 * h + 1] << 32);
}

// ---------------------------------------------------------------------------
// Prep kernel. Roles interleaved mod 2 (co-resident from the first wave):
//   bid&1==1 -> conv slice grp = bid/2 (item f32->fp8 + w1f8; pure stream)
//   bid&1==0 -> inter block grp = bid/2, handling TWO groups of 4 b each
//               (fitb staged ONCE -> halves fi re-read traffic), with the
//               ub projection computed per group from the u4 LDS rows.
// ---------------------------------------------------------------------------
__global__ __launch_bounds__(256)
void prep_kernel(const int* __restrict__ user_ids,
                 const int* __restrict__ item_ids,
                 const float* __restrict__ user_table,
                 const float* __restrict__ item_table,
                 const float* __restrict__ fi,
                 const float* __restrict__ w1,
                 const float* __restrict__ b1,
                 unsigned char* __restrict__ tbl8,
                 unsigned char* __restrict__ w1f8,
                 float* __restrict__ ub,
                 float* __restrict__ out_item,
                 float* __restrict__ out_inter) {
  __shared__ __align__(16) unsigned char ldsbuf[35392];
  const int t = threadIdx.x;
  const int role = blockIdx.x & 1;
  const int grp  = blockIdx.x >> 1;
  if (role == 1) {
    // ================= conv branch: pure streaming =========================
    const long t0 = (long)grp * 256 + t;
    const long total4 = (long)NITEMS * DIM / 4;
    const long stride = (long)CONV_BLKS * 256;
    for (long i = t0; i < total4; i += stride) {
      f32x4 v = ((const f32x4*)item_table)[i];
      int p = __builtin_amdgcn_cvt_pk_fp8_f32(v[0], v[1], 0, false);
      p     = __builtin_amdgcn_cvt_pk_fp8_f32(v[2], v[3], p, true);
      ((int*)tbl8)[i] = p;
    }
    if (t0 < 16384) {
      int L = (int)t0;
      int j = L & 7, gg = (L >> 3) & 3, mm = (L >> 5) & 15;
      int nt = (L >> 9) & 3, s = (L >> 11) & 3, part = (L >> 13) & 1;
      int kg = part * 128 + (s >> 1) * 64 + gg * 16 + (s & 1) * 8 + j;
      float v = w1[kg * AH + nt * 16 + mm];
      int pk = __builtin_amdgcn_cvt_pk_fp8_f32(v, v, 0, false);
      w1f8[L] = (unsigned char)(pk & 0xff);
    }
  } else {
    // ======== inter branch: 2 groups of 4 b, fitb staged once ==============
    unsigned short* fitb = (unsigned short*)ldsbuf;                 // [128*130]
    float (*u4)[DIM] = (float(*)[DIM])(ldsbuf + 33280);             // [4][128]
    float (*red)[4] = (float(*)[4])(ldsbuf + 35328);                // [4][4]
    for (int i = t; i < DIM * DIM; i += 256) {
      int d = i >> 7, e = i & 127;
      fitb[e * 130 + d] = f2bf(fi[i]);
    }
    const int col = t & 127;
    const int dh = t >> 7;
    const int lane = t & 63;
    const int wv = t >> 6;
    const unsigned short* fr = &fitb[col * 130 + dh * 64];

    for (int g2 = 0; g2 < 2; ++g2) {
      const int bb = grp * 8 + g2 * 4;
      __syncthreads();              // covers fitb staging / prev group usage
      for (int i = t; i < 4 * DIM; i += 256) {
        int bi = i >> 7, d = i & 127;
        u4[bi][d] = user_table[(long)user_ids[bb + bi] * DIM + d];
      }
      __syncthreads();

      // ub projection: thread t -> (bi = t>>6, n = t&63), u4 from LDS
      {
        const int bi = t >> 6;
        const int n = t & 63;
        float acc = b1[n];
#pragma unroll 8
        for (int d = 0; d < DIM; ++d)
          acc = fmaf(u4[bi][d], w1[d * AH + n], acc);
        ub[(long)(bb + bi) * AH + n] = acc;
      }

      float a0 = 0.f, a1 = 0.f, a2 = 0.f, a3 = 0.f;
#pragma unroll 4
      for (int d = 0; d < 64; d += 4) {
        float f0 = bf2f(fr[d]), f1 = bf2f(fr[d + 1]), f2 = bf2f(fr[d + 2]), f3 = bf2f(fr[d + 3]);
        f32x4 q0 = *(const f32x4*)&u4[0][dh * 64 + d];
        f32x4 q1 = *(const f32x4*)&u4[1][dh * 64 + d];
        f32x4 q2 = *(const f32x4*)&u4[2][dh * 64 + d];
        f32x4 q3 = *(const f32x4*)&u4[3][dh * 64 + d];
        a0 = fmaf(f0, q0[0], a0); a0 = fmaf(f1, q0[1], a0); a0 = fmaf(f2, q0[2], a0); a0 = fmaf(f3, q0[3], a0);
        a1 = fmaf(f0, q1[0], a1); a1 = fmaf(f1, q1[1], a1); a1 = fmaf(f2, q1[2], a1); a1 = fmaf(f3, q1[3], a1);
        a2 = fmaf(f0, q2[0], a2); a2 = fmaf(f1, q2[1], a2); a2 = fmaf(f2, q2[2], a2); a2 = fmaf(f3, q2[3], a2);
        a3 = fmaf(f0, q3[0], a3); a3 = fmaf(f1, q3[1], a3); a3 = fmaf(f2, q3[2], a3); a3 = fmaf(f3, q3[3], a3);
      }
      const float vv0 = item_table[(long)item_ids[bb + 0] * DIM + col];
      const float vv1 = item_table[(long)item_ids[bb + 1] * DIM + col];
      const float vv2 = item_table[(long)item_ids[bb + 2] * DIM + col];
      const float vv3 = item_table[(long)item_ids[bb + 3] * DIM + col];
      if (dh == 0) {
        out_item[(long)(bb + 0) * DIM + col] = vv0;
        out_item[(long)(bb + 1) * DIM + col] = vv1;
        out_item[(long)(bb + 2) * DIM + col] = vv2;
        out_item[(long)(bb + 3) * DIM + col] = vv3;
      }
      float p0 = a0 * vv0, p1 = a1 * vv1, p2 = a2 * vv2, p3 = a3 * vv3;
#pragma unroll
      for (int msk = 1; msk <= 32; msk <<= 1) {
        p0 += __shfl_xor(p0, msk);
        p1 += __shfl_xor(p1, msk);
        p2 += __shfl_xor(p2, msk);
        p3 += __shfl_xor(p3, msk);
      }
      if (lane == 0) { red[wv][0] = p0; red[wv][1] = p1; red[wv][2] = p2; red[wv][3] = p3; }
      __syncthreads();
      if (t < 4)
        out_inter[bb + t] = red[0][t] + red[1][t] + red[2][t] + red[3][t];
    }
  }
}

// ---------------------------------------------------------------------------
// Gather kernel — byte-identical to r13/r14/r15 (measured 65.3us): r2 body,
// ub precomputed, ZERO LDS, no barriers. One wave per batch element,
// 13 tiles, register gather ring: 4 buffers, prefetch distance 3.
// ---------------------------------------------------------------------------
__global__ __launch_bounds__(256)
void gather_kernel(const int* __restrict__ user_ids,
                   const int* __restrict__ user_history,
                   const float* __restrict__ user_table,
                   const unsigned char* __restrict__ tbl8,
                   const unsigned char* __restrict__ w1f8,
                   const float* __restrict__ ub,
                   const float* __restrict__ w2,
                   const float* __restrict__ b2,
                   float* __restrict__ out_user) {
  const int lane = threadIdx.x & 63;
  const int wave = threadIdx.x >> 6;
  const int b = blockIdx.x * 4 + wave;
  const int m = lane & 15;
  const int g = lane >> 4;

  const int uid = __builtin_amdgcn_readfirstlane(user_ids[b]);
  const float* urow = user_table + (long)uid * DIM;
  const int* hrow = user_history + (long)b * HLEN;

  int idxs[NTILE];
#pragma unroll
  for (int tt = 0; tt < NTILE; ++tt) {
    int row = tt * 16 + m;
    idxs[tt] = (row < HLEN) ? hrow[row] : 0;
  }

  i32x4 pa[4][2];
#define LOADT(T, BUF)                                                          \
  {                                                                            \
    const unsigned char* p_ = tbl8 + ((long)idxs[T] << 7) + g * 16;            \
    pa[BUF][0] = *(const i32x4*)p_;                                            \
    pa[BUF][1] = *(const i32x4*)(p_ + 64);                                     \
  }
  LOADT(0, 0) LOADT(1, 1) LOADT(2, 2)

  const unsigned char* wbot = w1f8 + 8192;
  long bfr[4][4];
#pragma unroll
  for (int s = 0; s < 4; ++s)
#pragma unroll
    for (int nt = 0; nt < 4; ++nt)
      bfr[s][nt] = *(const long*)(wbot + ((s * 4 + nt) * 16 + m) * 32 + g * 8);
  float ubreg[4], w2reg[4];
#pragma unroll
  for (int nt = 0; nt < 4; ++nt) {
    ubreg[nt] = ub[(long)b * AH + nt * 16 + m];
    w2reg[nt] = w2[nt * 16 + m];
  }
  const float b2v = b2[0];

  float arep[32];
#pragma unroll
  for (int c = 0; c < 32; ++c) arep[c] = 0.f;

#pragma unroll
  for (int tt = 0; tt < NTILE; ++tt) {
    if (tt + 3 < NTILE) LOADT(tt + 3, (tt + 3) & 3)
    const int cb = tt & 3;

    f32x4 acc[4];
#pragma unroll
    for (int nt = 0; nt < 4; ++nt) acc[nt] = (f32x4){0.f, 0.f, 0.f, 0.f};
#pragma unroll
    for (int s = 0; s < 4; ++s) {
      long a_s = pick64(pa[cb][s >> 1], s & 1);
#pragma unroll
      for (int nt = 0; nt < 4; ++nt)
        acc[nt] = __builtin_amdgcn_mfma_f32_16x16x32_fp8_fp8(a_s, bfr[s][nt], acc[nt], 0, 0, 0);
    }

    float sums[4];
#pragma unroll
    for (int r = 0; r < 4; ++r) {
      float s = 0.f;
#pragma unroll
      for (int nt = 0; nt < 4; ++nt) {
        float hh = fmaxf(acc[nt][r] + ubreg[nt], 0.f);
        s = fmaf(hh, w2reg[nt], s);
      }
      s += __shfl_xor(s, 1);
      s += __shfl_xor(s, 2);
      s += __shfl_xor(s, 4);
      s += __shfl_xor(s, 8);
      sums[r] = s;
    }
    const int q = m & 3;
    float keep = (q == 0) ? sums[0] : (q == 1) ? sums[1] : (q == 2) ? sums[2] : sums[3];
    float sv = __shfl(keep, ((m >> 2) << 4) | m);
    float attw = 1.f / (1.f + __expf(-(sv + b2v)));
    if (tt * 16 + m >= HLEN) attw = 0.f;

#pragma unroll
    for (int kb = 0; kb < 2; ++kb)
#pragma unroll
      for (int d = 0; d < 4; ++d) {
        f32x2 lo = __builtin_amdgcn_cvt_pk_f32_fp8(pa[cb][kb][d], false);
        f32x2 hi = __builtin_amdgcn_cvt_pk_f32_fp8(pa[cb][kb][d], true);
        const int base = kb * 16 + d * 4;
        arep[base + 0] = fmaf(attw, lo[0], arep[base + 0]);
        arep[base + 1] = fmaf(attw, lo[1], arep[base + 1]);
        arep[base + 2] = fmaf(attw, hi[0], arep[base + 2]);
        arep[base + 3] = fmaf(attw, hi[1], arep[base + 3]);
      }
  }
#undef LOADT

#pragma unroll
  for (int c = 0; c < 32; ++c) {
    arep[c] += __shfl_xor(arep[c], 1);
    arep[c] += __shfl_xor(arep[c], 2);
    arep[c] += __shfl_xor(arep[c], 4);
    arep[c] += __shfl_xor(arep[c], 8);
  }
  if (m == 0) {
#pragma unroll
    for (int kb = 0; kb < 2; ++kb)
#pragma unroll
      for (int i4 = 0; i4 < 4; ++i4) {
        const int col = kb * 64 + g * 16 + i4 * 4;
        f32x4 uv = *(const f32x4*)(urow + col);
        f32x4 o;
#pragma unroll
        for (int qq = 0; qq < 4; ++qq) o[qq] = uv[qq] + arep[kb * 16 + i4 * 4 + qq];
        *(f32x4*)(out_user + (long)b * DIM + col) = o;
      }
  }
}

// ---------------------------------------------------------------------------
// Fallback path (ws too small): r1-verified bf16-inline main + inter.
// ---------------------------------------------------------------------------
__global__ __launch_bounds__(256)
void main_fallback(const int* __restrict__ user_ids,
                   const int* __restrict__ user_history,
                   const float* __restrict__ user_table,
                   const float* __restrict__ item_table,
                   const float* __restrict__ w1,
                   const float* __restrict__ b1,
                   const float* __restrict__ w2,
                   const float* __restrict__ b2,
                   float* __restrict__ out_user) {
  const int lane = threadIdx.x & 63;
  const int wave = threadIdx.x >> 6;
  const int b = blockIdx.x * 4 + wave;
  const int m = lane & 15, g = lane >> 4;
  const int uid = __builtin_amdgcn_readfirstlane(user_ids[b]);
  const float* urow = user_table + (long)uid * DIM;
  float upj = b1[lane];
#pragma unroll 8
  for (int d = 0; d < DIM; ++d) upj = fmaf(urow[d], w1[d * AH + lane], upj);
  bf16x8 bfr[4][4];
#pragma unroll
  for (int ks = 0; ks < 4; ++ks)
#pragma unroll
    for (int nt = 0; nt < 4; ++nt) {
      bf16x8 bv;
#pragma unroll
      for (int j = 0; j < 8; ++j)
        bv[j] = (short)f2bf(w1[(DIM + ks * 32 + g * 8 + j) * AH + nt * 16 + m]);
      bfr[ks][nt] = bv;
    }
  float ubreg[4], w2reg[4];
#pragma unroll
  for (int nt = 0; nt < 4; ++nt) {
    ubreg[nt] = __shfl(upj, nt * 16 + m);
    w2reg[nt] = w2[nt * 16 + m];
  }
  const float b2v = b2[0];
  float arep[32];
#pragma unroll
  for (int c = 0; c < 32; ++c) arep[c] = 0.f;
  const int* hrow = user_history + (long)b * HLEN;
  for (int tt = 0; tt < NTILE; ++tt) {
    const int row = tt * 16 + m;
    const int idx = (row < HLEN) ? hrow[row] : 0;
    bf16x8 a[4];
    const float* rp = item_table + (long)idx * DIM;
#pragma unroll
    for (int ks = 0; ks < 4; ++ks) {
      f32x4 lo = *(const f32x4*)(rp + ks * 32 + g * 8);
      f32x4 hi = *(const f32x4*)(rp + ks * 32 + g * 8 + 4);
      bf16x8 av;
      av[0] = (short)f2bf(lo[0]); av[1] = (short)f2bf(lo[1]);
      av[2] = (short)f2bf(lo[2]); av[3] = (short)f2bf(lo[3]);
      av[4] = (short)f2bf(hi[0]); av[5] = (short)f2bf(hi[1]);
      av[6] = (short)f2bf(hi[2]); av[7] = (short)f2bf(hi[3]);
      a[ks] = av;
    }
    f32x4 acc[4];
#pragma unroll
    for (int nt = 0; nt < 4; ++nt) acc[nt] = (f32x4){0.f, 0.f, 0.f, 0.f};
#pragma unroll
    for (int ks = 0; ks < 4; ++ks)
#pragma unroll
      for (int nt = 0; nt < 4; ++nt)
        acc[nt] = __builtin_amdgcn_mfma_f32_16x16x32_bf16(a[ks], bfr[ks][nt], acc[nt], 0, 0, 0);
    float sums[4];
#pragma unroll
    for (int r = 0; r < 4; ++r) {
      float s = 0.f;
#pragma unroll
      for (int nt = 0; nt < 4; ++nt) {
        float hh = fmaxf(acc[nt][r] + ubreg[nt], 0.f);
        s = fmaf(hh, w2reg[nt], s);
      }
      s += __shfl_xor(s, 1); s += __shfl_xor(s, 2);
      s += __shfl_xor(s, 4); s += __shfl_xor(s, 8);
      sums[r] = s;
    }
    const int q = m & 3;
    float keep = (q == 0) ? sums[0] : (q == 1) ? sums[1] : (q == 2) ? sums[2] : sums[3];
    float sv = __shfl(keep, ((m >> 2) << 4) | m);
    float attw = 1.f / (1.f + __expf(-(sv + b2v)));
    if (row >= HLEN) attw = 0.f;
#pragma unroll
    for (int ks = 0; ks < 4; ++ks)
#pragma unroll
      for (int j = 0; j < 8; ++j)
        arep[ks * 8 + j] = fmaf(attw, bf2f((unsigned short)a[ks][j]), arep[ks * 8 + j]);
  }
#pragma unroll
  for (int c = 0; c < 32; ++c) {
    arep[c] += __shfl_xor(arep[c], 1);
    arep[c] += __shfl_xor(arep[c], 2);
    arep[c] += __shfl_xor(arep[c], 4);
    arep[c] += __shfl_xor(arep[c], 8);
  }
  if (m == 0) {
#pragma unroll
    for (int ks = 0; ks < 4; ++ks)
#pragma unroll
      for (int j = 0; j < 8; ++j) {
        const int col = ks * 32 + g * 8 + j;
        out_user[(long)b * DIM + col] = urow[col] + arep[ks * 8 + j];
      }
  }
}

__global__ __launch_bounds__(256)
void inter_kernel(const int* __restrict__ user_ids,
                  const int* __restrict__ item_ids,
                  const float* __restrict__ user_table,
                  const float* __restrict__ item_table,
                  const float* __restrict__ fi,
                  float* __restrict__ out_item,
                  float* __restrict__ out_inter) {
  __shared__ unsigned short fitb[DIM * 130];
  __shared__ float u4[4][DIM];
  __shared__ float red[4][4];
  const int t = threadIdx.x;
  for (int i = t; i < DIM * DIM; i += 256) {
    int d = i >> 7, e = i & 127;
    fitb[e * 130 + d] = f2bf(fi[i]);
  }
  const int col = t & 127;
  const int dh = t >> 7;
  const int lane = t & 63;
  const int wv = t >> 6;
  const int bb = blockIdx.x * 4;
  for (int i = t; i < 4 * DIM; i += 256) {
    int bi = i >> 7, d = i & 127;
    u4[bi][d] = user_table[(long)user_ids[bb + bi] * DIM + d];
  }
  __syncthreads();
  const unsigned short* fr = &fitb[col * 130 + dh * 64];
  float a0 = 0.f, a1 = 0.f, a2 = 0.f, a3 = 0.f;
#pragma unroll 4
  for (int d = 0; d < 64; d += 4) {
    float f0 = bf2f(fr[d]), f1 = bf2f(fr[d + 1]), f2 = bf2f(fr[d + 2]), f3 = bf2f(fr[d + 3]);
    f32x4 q0 = *(const f32x4*)&u4[0][dh * 64 + d];
    f32x4 q1 = *(const f32x4*)&u4[1][dh * 64 + d];
    f32x4 q2 = *(const f32x4*)&u4[2][dh * 64 + d];
    f32x4 q3 = *(const f32x4*)&u4[3][dh * 64 + d];
    a0 = fmaf(f0, q0[0], a0); a0 = fmaf(f1, q0[1], a0); a0 = fmaf(f2, q0[2], a0); a0 = fmaf(f3, q0[3], a0);
    a1 = fmaf(f0, q1[0], a1); a1 = fmaf(f1, q1[1], a1); a1 = fmaf(f2, q1[2], a1); a1 = fmaf(f3, q1[3], a1);
    a2 = fmaf(f0, q2[0], a2); a2 = fmaf(f1, q2[1], a2); a2 = fmaf(f2, q2[2], a2); a2 = fmaf(f3, q2[3], a2);
    a3 = fmaf(f0, q3[0], a3); a3 = fmaf(f1, q3[1], a3); a3 = fmaf(f2, q3[2], a3); a3 = fmaf(f3, q3[3], a3);
  }
  const float vv0 = item_table[(long)item_ids[bb + 0] * DIM + col];
  const float vv1 = item_table[(long)item_ids[bb + 1] * DIM + col];
  const float vv2 = item_table[(long)item_ids[bb + 2] * DIM + col];
  const float vv3 = item_table[(long)item_ids[bb + 3] * DIM + col];
  if (dh == 0) {
    out_item[(long)(bb + 0) * DIM + col] = vv0;
    out_item[(long)(bb + 1) * DIM + col] = vv1;
    out_item[(long)(bb + 2) * DIM + col] = vv2;
    out_item[(long)(bb + 3) * DIM + col] = vv3;
  }
  float p0 = a0 * vv0, p1 = a1 * vv1, p2 = a2 * vv2, p3 = a3 * vv3;
#pragma unroll
  for (int msk = 1; msk <= 32; msk <<= 1) {
    p0 += __shfl_xor(p0, msk);
    p1 += __shfl_xor(p1, msk);
    p2 += __shfl_xor(p2, msk);
    p3 += __shfl_xor(p3, msk);
  }
  if (lane == 0) { red[wv][0] = p0; red[wv][1] = p1; red[wv][2] = p2; red[wv][3] = p3; }
  __syncthreads();
  if (t < 4)
    out_inter[bb + t] = red[0][t] + red[1][t] + red[2][t] + red[3][t];
}

// ---------------------------------------------------------------------------
extern "C" void kernel_launch(void* const* d_in, const int* in_sizes, int n_in,
                              void* d_out, int out_size, void* d_ws, size_t ws_size,
                              hipStream_t stream) {
  const int*   user_ids     = (const int*)d_in[0];
  const int*   item_ids     = (const int*)d_in[1];
  const int*   user_history = (const int*)d_in[2];
  const float* user_table   = (const float*)d_in[3];
  const float* item_table   = (const float*)d_in[4];
  const float* fi           = (const float*)d_in[5];
  const float* w1           = (const float*)d_in[6];
  const float* b1           = (const float*)d_in[7];
  const float* w2           = (const float*)d_in[8];
  const float* b2           = (const float*)d_in[9];

  float* out       = (float*)d_out;
  float* out_user  = out;
  float* out_item  = out + (size_t)NB * DIM;
  float* out_inter = out + (size_t)2 * NB * DIM;

  const size_t tbl8_b = (size_t)NITEMS * DIM;     // 12.8 MB
  const size_t w1f8_b = 16384;
  const size_t ub_b   = (size_t)NB * AH * 4;      // 2 MB
  const size_t need = tbl8_b + w1f8_b + ub_b;     // ~14.8 MB

  if (ws_size >= need) {
    unsigned char* tbl8 = (unsigned char*)d_ws;
    unsigned char* w1f8 = tbl8 + tbl8_b;
    float* ub = (float*)(w1f8 + w1f8_b);
    prep_kernel<<<PREP_BLKS, 256, 0, stream>>>(user_ids, item_ids,
        user_table, item_table, fi, w1, b1, tbl8, w1f8, ub, out_item, out_inter);
    gather_kernel<<<NB / 4, 256, 0, stream>>>(user_ids, user_history, user_table,
        tbl8, w1f8, ub, w2, b2, out_user);
  } else {
    main_fallback<<<NB / 4, 256, 0, stream>>>(user_ids, user_history, user_table,
        item_table, w1, b1, w2, b2, out_user);
    inter_kernel<<<NB / 4, 256, 0, stream>>>(user_ids, item_ids, user_table,
        item_table, fi, out_item, out_inter);
  }
}

// Round 17
// 96.446 us; speedup vs baseline: 1.1053x; 1.1053x over previous
//
#include <hip/hip_runtime.h>
#include <math.h>

#define NB      8192
#define HLEN    200
#define DIM     128
#define AH      64
#define NITEMS  100000
#define NTILE   13
#define CONV_BLKS 1024
#define INTER_BLKS (NB / 4)    // 2048
#define PREP_BLKS (CONV_BLKS + INTER_BLKS)   // 3072, roles interleaved mod 3

typedef __attribute__((ext_vector_type(4))) float f32x4;
typedef __attribute__((ext_vector_type(2))) float f32x2;
typedef __attribute__((ext_vector_type(4))) int   i32x4;
typedef __attribute__((ext_vector_type(8))) short bf16x8;
typedef unsigned int uint;

__device__ __forceinline__ unsigned short f2bf(float f) {
  uint u = __float_as_uint(f);
  u += 0x7fffu + ((u >> 16) & 1u);
  return (unsigned short)(u >> 16);
}
__device__ __forceinline__ float bf2f(unsigned short h) {
  return __uint_as_float(((uint)h) << 16);
}
__device__ __forceinline__ long pick64(const i32x4& v, int h) {
  return (long)(unsigned)v[2 * h] | ((long)(unsigned)v[2 * h + 1] << 32);
}

// ---------------------------------------------------------------------------
// Prep kernel (r15-verified, 96.5us total). Roles interleaved mod 3 so conv
// (HBM-stream) and inter (LDS/VALU) blocks are co-resident from the first
// scheduling wave:
//   bid%3==2 -> conv slice cb = bid/3   (item f32->fp8 + w1f8; pure stream)
//   else     -> inter group ib = (bid/3)*2 + bid%3 (bilinear + item copy
//               + ub projection for its 4 b's, using the u4 LDS rows)
// ---------------------------------------------------------------------------
__global__ __launch_bounds__(256)
void prep_kernel(const int* __restrict__ user_ids,
                 const int* __restrict__ item_ids,
                 const float* __restrict__ user_table,
                 const float* __restrict__ item_table,
                 const float* __restrict__ fi,
                 const float* __restrict__ w1,
                 const float* __restrict__ b1,
                 unsigned char* __restrict__ tbl8,
                 unsigned char* __restrict__ w1f8,
                 float* __restrict__ ub,
                 float* __restrict__ out_item,
                 float* __restrict__ out_inter) {
  __shared__ __align__(16) unsigned char ldsbuf[35392];
  const int t = threadIdx.x;
  const int role = blockIdx.x % 3;
  const int grp  = blockIdx.x / 3;
  if (role == 2) {
    // ================= conv branch: pure streaming =========================
    const long t0 = (long)grp * 256 + t;
    const long total4 = (long)NITEMS * DIM / 4;
    const long stride = (long)CONV_BLKS * 256;
    for (long i = t0; i < total4; i += stride) {
      f32x4 v = ((const f32x4*)item_table)[i];
      int p = __builtin_amdgcn_cvt_pk_fp8_f32(v[0], v[1], 0, false);
      p     = __builtin_amdgcn_cvt_pk_fp8_f32(v[2], v[3], p, true);
      ((int*)tbl8)[i] = p;
    }
    if (t0 < 16384) {
      int L = (int)t0;
      int j = L & 7, gg = (L >> 3) & 3, mm = (L >> 5) & 15;
      int nt = (L >> 9) & 3, s = (L >> 11) & 3, part = (L >> 13) & 1;
      int kg = part * 128 + (s >> 1) * 64 + gg * 16 + (s & 1) * 8 + j;
      float v = w1[kg * AH + nt * 16 + mm];
      int pk = __builtin_amdgcn_cvt_pk_fp8_f32(v, v, 0, false);
      w1f8[L] = (unsigned char)(pk & 0xff);
    }
  } else {
    // ================= inter branch + ub projection ========================
    unsigned short* fitb = (unsigned short*)ldsbuf;                 // [128*130]
    float (*u4)[DIM] = (float(*)[DIM])(ldsbuf + 33280);             // [4][128]
    float (*red)[4] = (float(*)[4])(ldsbuf + 35328);                // [4][4]
    for (int i = t; i < DIM * DIM; i += 256) {
      int d = i >> 7, e = i & 127;
      fitb[e * 130 + d] = f2bf(fi[i]);
    }
    const int col = t & 127;
    const int dh = t >> 7;
    const int lane = t & 63;
    const int wv = t >> 6;
    const int ib = grp * 2 + role;
    const int bb = ib * 4;
    for (int i = t; i < 4 * DIM; i += 256) {
      int bi = i >> 7, d = i & 127;
      u4[bi][d] = user_table[(long)user_ids[bb + bi] * DIM + d];
    }
    __syncthreads();

    // ---- ub projection: thread t -> (bi = t>>6, n = t&63), u4 from LDS ----
    {
      const int bi = t >> 6;
      const int n = t & 63;
      float acc = b1[n];
#pragma unroll 8
      for (int d = 0; d < DIM; ++d)
        acc = fmaf(u4[bi][d], w1[d * AH + n], acc);
      ub[(long)(bb + bi) * AH + n] = acc;
    }

    const unsigned short* fr = &fitb[col * 130 + dh * 64];
    float a0 = 0.f, a1 = 0.f, a2 = 0.f, a3 = 0.f;
#pragma unroll 4
    for (int d = 0; d < 64; d += 4) {
      float f0 = bf2f(fr[d]), f1 = bf2f(fr[d + 1]), f2 = bf2f(fr[d + 2]), f3 = bf2f(fr[d + 3]);
      f32x4 q0 = *(const f32x4*)&u4[0][dh * 64 + d];
      f32x4 q1 = *(const f32x4*)&u4[1][dh * 64 + d];
      f32x4 q2 = *(const f32x4*)&u4[2][dh * 64 + d];
      f32x4 q3 = *(const f32x4*)&u4[3][dh * 64 + d];
      a0 = fmaf(f0, q0[0], a0); a0 = fmaf(f1, q0[1], a0); a0 = fmaf(f2, q0[2], a0); a0 = fmaf(f3, q0[3], a0);
      a1 = fmaf(f0, q1[0], a1); a1 = fmaf(f1, q1[1], a1); a1 = fmaf(f2, q1[2], a1); a1 = fmaf(f3, q1[3], a1);
      a2 = fmaf(f0, q2[0], a2); a2 = fmaf(f1, q2[1], a2); a2 = fmaf(f2, q2[2], a2); a2 = fmaf(f3, q2[3], a2);
      a3 = fmaf(f0, q3[0], a3); a3 = fmaf(f1, q3[1], a3); a3 = fmaf(f2, q3[2], a3); a3 = fmaf(f3, q3[3], a3);
    }
    const float vv0 = item_table[(long)item_ids[bb + 0] * DIM + col];
    const float vv1 = item_table[(long)item_ids[bb + 1] * DIM + col];
    const float vv2 = item_table[(long)item_ids[bb + 2] * DIM + col];
    const float vv3 = item_table[(long)item_ids[bb + 3] * DIM + col];
    if (dh == 0) {
      out_item[(long)(bb + 0) * DIM + col] = vv0;
      out_item[(long)(bb + 1) * DIM + col] = vv1;
      out_item[(long)(bb + 2) * DIM + col] = vv2;
      out_item[(long)(bb + 3) * DIM + col] = vv3;
    }
    float p0 = a0 * vv0, p1 = a1 * vv1, p2 = a2 * vv2, p3 = a3 * vv3;
#pragma unroll
    for (int msk = 1; msk <= 32; msk <<= 1) {
      p0 += __shfl_xor(p0, msk);
      p1 += __shfl_xor(p1, msk);
      p2 += __shfl_xor(p2, msk);
      p3 += __shfl_xor(p3, msk);
    }
    if (lane == 0) { red[wv][0] = p0; red[wv][1] = p1; red[wv][2] = p2; red[wv][3] = p3; }
    __syncthreads();
    if (t < 4)
      out_inter[bb + t] = red[0][t] + red[1][t] + red[2][t] + red[3][t];
  }
}

// ---------------------------------------------------------------------------
// Gather kernel — byte-identical to r13-r16 (measured 65.3us): r2 body, ub
// precomputed, ZERO LDS, no barriers. One wave per batch element, 13 tiles,
// register gather ring: 4 buffers, prefetch distance 3.
// ---------------------------------------------------------------------------
__global__ __launch_bounds__(256)
void gather_kernel(const int* __restrict__ user_ids,
                   const int* __restrict__ user_history,
                   const float* __restrict__ user_table,
                   const unsigned char* __restrict__ tbl8,
                   const unsigned char* __restrict__ w1f8,
                   const float* __restrict__ ub,
                   const float* __restrict__ w2,
                   const float* __restrict__ b2,
                   float* __restrict__ out_user) {
  const int lane = threadIdx.x & 63;
  const int wave = threadIdx.x >> 6;
  const int b = blockIdx.x * 4 + wave;
  const int m = lane & 15;
  const int g = lane >> 4;

  const int uid = __builtin_amdgcn_readfirstlane(user_ids[b]);
  const float* urow = user_table + (long)uid * DIM;
  const int* hrow = user_history + (long)b * HLEN;

  int idxs[NTILE];
#pragma unroll
  for (int tt = 0; tt < NTILE; ++tt) {
    int row = tt * 16 + m;
    idxs[tt] = (row < HLEN) ? hrow[row] : 0;
  }

  i32x4 pa[4][2];
#define LOADT(T, BUF)                                                          \
  {                                                                            \
    const unsigned char* p_ = tbl8 + ((long)idxs[T] << 7) + g * 16;            \
    pa[BUF][0] = *(const i32x4*)p_;                                            \
    pa[BUF][1] = *(const i32x4*)(p_ + 64);                                     \
  }
  LOADT(0, 0) LOADT(1, 1) LOADT(2, 2)

  const unsigned char* wbot = w1f8 + 8192;
  long bfr[4][4];
#pragma unroll
  for (int s = 0; s < 4; ++s)
#pragma unroll
    for (int nt = 0; nt < 4; ++nt)
      bfr[s][nt] = *(const long*)(wbot + ((s * 4 + nt) * 16 + m) * 32 + g * 8);
  float ubreg[4], w2reg[4];
#pragma unroll
  for (int nt = 0; nt < 4; ++nt) {
    ubreg[nt] = ub[(long)b * AH + nt * 16 + m];
    w2reg[nt] = w2[nt * 16 + m];
  }
  const float b2v = b2[0];

  float arep[32];
#pragma unroll
  for (int c = 0; c < 32; ++c) arep[c] = 0.f;

#pragma unroll
  for (int tt = 0; tt < NTILE; ++tt) {
    if (tt + 3 < NTILE) LOADT(tt + 3, (tt + 3) & 3)
    const int cb = tt & 3;

    f32x4 acc[4];
#pragma unroll
    for (int nt = 0; nt < 4; ++nt) acc[nt] = (f32x4){0.f, 0.f, 0.f, 0.f};
#pragma unroll
    for (int s = 0; s < 4; ++s) {
      long a_s = pick64(pa[cb][s >> 1], s & 1);
#pragma unroll
      for (int nt = 0; nt < 4; ++nt)
        acc[nt] = __builtin_amdgcn_mfma_f32_16x16x32_fp8_fp8(a_s, bfr[s][nt], acc[nt], 0, 0, 0);
    }

    float sums[4];
#pragma unroll
    for (int r = 0; r < 4; ++r) {
      float s = 0.f;
#pragma unroll
      for (int nt = 0; nt < 4; ++nt) {
        float hh = fmaxf(acc[nt][r] + ubreg[nt], 0.f);
        s = fmaf(hh, w2reg[nt], s);
      }
      s += __shfl_xor(s, 1);
      s += __shfl_xor(s, 2);
      s += __shfl_xor(s, 4);
      s += __shfl_xor(s, 8);
      sums[r] = s;
    }
    const int q = m & 3;
    float keep = (q == 0) ? sums[0] : (q == 1) ? sums[1] : (q == 2) ? sums[2] : sums[3];
    float sv = __shfl(keep, ((m >> 2) << 4) | m);
    float attw = 1.f / (1.f + __expf(-(sv + b2v)));
    if (tt * 16 + m >= HLEN) attw = 0.f;

#pragma unroll
    for (int kb = 0; kb < 2; ++kb)
#pragma unroll
      for (int d = 0; d < 4; ++d) {
        f32x2 lo = __builtin_amdgcn_cvt_pk_f32_fp8(pa[cb][kb][d], false);
        f32x2 hi = __builtin_amdgcn_cvt_pk_f32_fp8(pa[cb][kb][d], true);
        const int base = kb * 16 + d * 4;
        arep[base + 0] = fmaf(attw, lo[0], arep[base + 0]);
        arep[base + 1] = fmaf(attw, lo[1], arep[base + 1]);
        arep[base + 2] = fmaf(attw, hi[0], arep[base + 2]);
        arep[base + 3] = fmaf(attw, hi[1], arep[base + 3]);
      }
  }
#undef LOADT

#pragma unroll
  for (int c = 0; c < 32; ++c) {
    arep[c] += __shfl_xor(arep[c], 1);
    arep[c] += __shfl_xor(arep[c], 2);
    arep[c] += __shfl_xor(arep[c], 4);
    arep[c] += __shfl_xor(arep[c], 8);
  }
  if (m == 0) {
#pragma unroll
    for (int kb = 0; kb < 2; ++kb)
#pragma unroll
      for (int i4 = 0; i4 < 4; ++i4) {
        const int col = kb * 64 + g * 16 + i4 * 4;
        f32x4 uv = *(const f32x4*)(urow + col);
        f32x4 o;
#pragma unroll
        for (int qq = 0; qq < 4; ++qq) o[qq] = uv[qq] + arep[kb * 16 + i4 * 4 + qq];
        *(f32x4*)(out_user + (long)b * DIM + col) = o;
      }
  }
}

// ---------------------------------------------------------------------------
// Fallback path (ws too small): r1-verified bf16-inline main + inter.
// ---------------------------------------------------------------------------
__global__ __launch_bounds__(256)
void main_fallback(const int* __restrict__ user_ids,
                   const int* __restrict__ user_history,
                   const float* __restrict__ user_table,
                   const float* __restrict__ item_table,
                   const float* __restrict__ w1,
                   const float* __restrict__ b1,
                   const float* __restrict__ w2,
                   const float* __restrict__ b2,
                   float* __restrict__ out_user) {
  const int lane = threadIdx.x & 63;
  const int wave = threadIdx.x >> 6;
  const int b = blockIdx.x * 4 + wave;
  const int m = lane & 15, g = lane >> 4;
  const int uid = __builtin_amdgcn_readfirstlane(user_ids[b]);
  const float* urow = user_table + (long)uid * DIM;
  float upj = b1[lane];
#pragma unroll 8
  for (int d = 0; d < DIM; ++d) upj = fmaf(urow[d], w1[d * AH + lane], upj);
  bf16x8 bfr[4][4];
#pragma unroll
  for (int ks = 0; ks < 4; ++ks)
#pragma unroll
    for (int nt = 0; nt < 4; ++nt) {
      bf16x8 bv;
#pragma unroll
      for (int j = 0; j < 8; ++j)
        bv[j] = (short)f2bf(w1[(DIM + ks * 32 + g * 8 + j) * AH + nt * 16 + m]);
      bfr[ks][nt] = bv;
    }
  float ubreg[4], w2reg[4];
#pragma unroll
  for (int nt = 0; nt < 4; ++nt) {
    ubreg[nt] = __shfl(upj, nt * 16 + m);
    w2reg[nt] = w2[nt * 16 + m];
  }
  const float b2v = b2[0];
  float arep[32];
#pragma unroll
  for (int c = 0; c < 32; ++c) arep[c] = 0.f;
  const int* hrow = user_history + (long)b * HLEN;
  for (int tt = 0; tt < NTILE; ++tt) {
    const int row = tt * 16 + m;
    const int idx = (row < HLEN) ? hrow[row] : 0;
    bf16x8 a[4];
    const float* rp = item_table + (long)idx * DIM;
#pragma unroll
    for (int ks = 0; ks < 4; ++ks) {
      f32x4 lo = *(const f32x4*)(rp + ks * 32 + g * 8);
      f32x4 hi = *(const f32x4*)(rp + ks * 32 + g * 8 + 4);
      bf16x8 av;
      av[0] = (short)f2bf(lo[0]); av[1] = (short)f2bf(lo[1]);
      av[2] = (short)f2bf(lo[2]); av[3] = (short)f2bf(lo[3]);
      av[4] = (short)f2bf(hi[0]); av[5] = (short)f2bf(hi[1]);
      av[6] = (short)f2bf(hi[2]); av[7] = (short)f2bf(hi[3]);
      a[ks] = av;
    }
    f32x4 acc[4];
#pragma unroll
    for (int nt = 0; nt < 4; ++nt) acc[nt] = (f32x4){0.f, 0.f, 0.f, 0.f};
#pragma unroll
    for (int ks = 0; ks < 4; ++ks)
#pragma unroll
      for (int nt = 0; nt < 4; ++nt)
        acc[nt] = __builtin_amdgcn_mfma_f32_16x16x32_bf16(a[ks], bfr[ks][nt], acc[nt], 0, 0, 0);
    float sums[4];
#pragma unroll
    for (int r = 0; r < 4; ++r) {
      float s = 0.f;
#pragma unroll
      for (int nt = 0; nt < 4; ++nt) {
        float hh = fmaxf(acc[nt][r] + ubreg[nt], 0.f);
        s = fmaf(hh, w2reg[nt], s);
      }
      s += __shfl_xor(s, 1); s += __shfl_xor(s, 2);
      s += __shfl_xor(s, 4); s += __shfl_xor(s, 8);
      sums[r] = s;
    }
    const int q = m & 3;
    float keep = (q == 0) ? sums[0] : (q == 1) ? sums[1] : (q == 2) ? sums[2] : sums[3];
    float sv = __shfl(keep, ((m >> 2) << 4) | m);
    float attw = 1.f / (1.f + __expf(-(sv + b2v)));
    if (row >= HLEN) attw = 0.f;
#pragma unroll
    for (int ks = 0; ks < 4; ++ks)
#pragma unroll
      for (int j = 0; j < 8; ++j)
        arep[ks * 8 + j] = fmaf(attw, bf2f((unsigned short)a[ks][j]), arep[ks * 8 + j]);
  }
#pragma unroll
  for (int c = 0; c < 32; ++c) {
    arep[c] += __shfl_xor(arep[c], 1);
    arep[c] += __shfl_xor(arep[c], 2);
    arep[c] += __shfl_xor(arep[c], 4);
    arep[c] += __shfl_xor(arep[c], 8);
  }
  if (m == 0) {
#pragma unroll
    for (int ks = 0; ks < 4; ++ks)
#pragma unroll
      for (int j = 0; j < 8; ++j) {
        const int col = ks * 32 + g * 8 + j;
        out_user[(long)b * DIM + col] = urow[col] + arep[ks * 8 + j];
      }
  }
}

__global__ __launch_bounds__(256)
void inter_kernel(const int* __restrict__ user_ids,
                  const int* __restrict__ item_ids,
                  const float* __restrict__ user_table,
                  const float* __restrict__ item_table,
                  const float* __restrict__ fi,
                  float* __restrict__ out_item,
                  float* __restrict__ out_inter) {
  __shared__ unsigned short fitb[DIM * 130];
  __shared__ float u4[4][DIM];
  __shared__ float red[4][4];
  const int t = threadIdx.x;
  for (int i = t; i < DIM * DIM; i += 256) {
    int d = i >> 7, e = i & 127;
    fitb[e * 130 + d] = f2bf(fi[i]);
  }
  const int col = t & 127;
  const int dh = t >> 7;
  const int lane = t & 63;
  const int wv = t >> 6;
  const int bb = blockIdx.x * 4;
  for (int i = t; i < 4 * DIM; i += 256) {
    int bi = i >> 7, d = i & 127;
    u4[bi][d] = user_table[(long)user_ids[bb + bi] * DIM + d];
  }
  __syncthreads();
  const unsigned short* fr = &fitb[col * 130 + dh * 64];
  float a0 = 0.f, a1 = 0.f, a2 = 0.f, a3 = 0.f;
#pragma unroll 4
  for (int d = 0; d < 64; d += 4) {
    float f0 = bf2f(fr[d]), f1 = bf2f(fr[d + 1]), f2 = bf2f(fr[d + 2]), f3 = bf2f(fr[d + 3]);
    f32x4 q0 = *(const f32x4*)&u4[0][dh * 64 + d];
    f32x4 q1 = *(const f32x4*)&u4[1][dh * 64 + d];
    f32x4 q2 = *(const f32x4*)&u4[2][dh * 64 + d];
    f32x4 q3 = *(const f32x4*)&u4[3][dh * 64 + d];
    a0 = fmaf(f0, q0[0], a0); a0 = fmaf(f1, q0[1], a0); a0 = fmaf(f2, q0[2], a0); a0 = fmaf(f3, q0[3], a0);
    a1 = fmaf(f0, q1[0], a1); a1 = fmaf(f1, q1[1], a1); a1 = fmaf(f2, q1[2], a1); a1 = fmaf(f3, q1[3], a1);
    a2 = fmaf(f0, q2[0], a2); a2 = fmaf(f1, q2[1], a2); a2 = fmaf(f2, q2[2], a2); a2 = fmaf(f3, q2[3], a2);
    a3 = fmaf(f0, q3[0], a3); a3 = fmaf(f1, q3[1], a3); a3 = fmaf(f2, q3[2], a3); a3 = fmaf(f3, q3[3], a3);
  }
  const float vv0 = item_table[(long)item_ids[bb + 0] * DIM + col];
  const float vv1 = item_table[(long)item_ids[bb + 1] * DIM + col];
  const float vv2 = item_table[(long)item_ids[bb + 2] * DIM + col];
  const float vv3 = item_table[(long)item_ids[bb + 3] * DIM + col];
  if (dh == 0) {
    out_item[(long)(bb + 0) * DIM + col] = vv0;
    out_item[(long)(bb + 1) * DIM + col] = vv1;
    out_item[(long)(bb + 2) * DIM + col] = vv2;
    out_item[(long)(bb + 3) * DIM + col] = vv3;
  }
  float p0 = a0 * vv0, p1 = a1 * vv1, p2 = a2 * vv2, p3 = a3 * vv3;
#pragma unroll
  for (int msk = 1; msk <= 32; msk <<= 1) {
    p0 += __shfl_xor(p0, msk);
    p1 += __shfl_xor(p1, msk);
    p2 += __shfl_xor(p2, msk);
    p3 += __shfl_xor(p3, msk);
  }
  if (lane == 0) { red[wv][0] = p0; red[wv][1] = p1; red[wv][2] = p2; red[wv][3] = p3; }
  __syncthreads();
  if (t < 4)
    out_inter[bb + t] = red[0][t] + red[1][t] + red[2][t] + red[3][t];
}

// ---------------------------------------------------------------------------
extern "C" void kernel_launch(void* const* d_in, const int* in_sizes, int n_in,
                              void* d_out, int out_size, void* d_ws, size_t ws_size,
                              hipStream_t stream) {
  const int*   user_ids     = (const int*)d_in[0];
  const int*   item_ids     = (const int*)d_in[1];
  const int*   user_history = (const int*)d_in[2];
  const float* user_table   = (const float*)d_in[3];
  const float* item_table   = (const float*)d_in[4];
  const float* fi           = (const float*)d_in[5];
  const float* w1           = (const float*)d_in[6];
  const float* b1           = (const float*)d_in[7];
  const float* w2           = (const float*)d_in[8];
  const float* b2           = (const float*)d_in[9];

  float* out       = (float*)d_out;
  float* out_user  = out;
  float* out_item  = out + (size_t)NB * DIM;
  float* out_inter = out + (size_t)2 * NB * DIM;

  const size_t tbl8_b = (size_t)NITEMS * DIM;     // 12.8 MB
  const size_t w1f8_b = 16384;
  const size_t ub_b   = (size_t)NB * AH * 4;      // 2 MB
  const size_t need = tbl8_b + w1f8_b + ub_b;     // ~14.8 MB

  if (ws_size >= need) {
    unsigned char* tbl8 = (unsigned char*)d_ws;
    unsigned char* w1f8 = tbl8 + tbl8_b;
    float* ub = (float*)(w1f8 + w1f8_b);
    prep_kernel<<<PREP_BLKS, 256, 0, stream>>>(user_ids, item_ids,
        user_table, item_table, fi, w1, b1, tbl8, w1f8, ub, out_item, out_inter);
    gather_kernel<<<NB / 4, 256, 0, stream>>>(user_ids, user_history, user_table,
        tbl8, w1f8, ub, w2, b2, out_user);
  } else {
    main_fallback<<<NB / 4, 256, 0, stream>>>(user_ids, user_history, user_table,
        item_table, w1, b1, w2, b2, out_user);
    inter_kernel<<<NB / 4, 256, 0, stream>>>(user_ids, item_ids, user_table,
        item_table, fi, out_item, out_inter);
  }
}